// Round 5
// baseline (133.269 us; speedup 1.0000x reference)
//
#include <hip/hip_runtime.h>
#include <math.h>

#define B_DIM 128
#define N_DIM 512
#define D_DIM 512
#define H_DIM 256
#define K_SEL 8

typedef __bf16 bf16x8 __attribute__((ext_vector_type(8)));
typedef float  f32x4  __attribute__((ext_vector_type(4)));

__device__ __forceinline__ void gload_lds16(const void* g, void* l) {
    __builtin_amdgcn_global_load_lds((const __attribute__((address_space(1))) void*)g,
                                     (__attribute__((address_space(3))) void*)l, 16, 0, 0);
}

// ---------------- Kernel 0: prep W1 -> transposed bf16 3-way splits ----------------
__global__ __launch_bounds__(256) void prep_w1_kernel(
    const float* __restrict__ W1,
    __bf16* __restrict__ w1t_h,
    __bf16* __restrict__ w1t_m,
    __bf16* __restrict__ w1t_l)
{
    const int c = blockIdx.x;      // 256 cols
    const int t = threadIdx.x;     // 256 threads over k
    #pragma unroll
    for (int kk = 0; kk < D_DIM; kk += 256) {
        int k = kk + t;
        float x = W1[(size_t)k * H_DIM + c];
        __bf16 h = (__bf16)x;
        float r1 = x - (float)h;
        __bf16 m = (__bf16)r1;
        float r2 = r1 - (float)m;
        __bf16 l = (__bf16)r2;
        w1t_h[(size_t)c * D_DIM + k] = h;
        w1t_m[(size_t)c * D_DIM + k] = m;
        w1t_l[(size_t)c * D_DIM + k] = l;
    }
}

// ---------------- Kernel 1: bf16x3-split MFMA scorer, LDS-pipelined, conflict-free ----
// Grid: 512 WGs x 512 threads. WG = 128 rows x 256 cols. 8 waves 2Mx4N, per-wave 64x64.
// LDS layouts are chunk-major (chunk16 = bf16x8):
//   A[kchunk 0..3][row 0..127]  -> linear chunk = kchunk*128 + row  (24 KB x2 buf x3 split)
//   B[kchunk 0..3][col 0..255]  -> linear chunk = kchunk*256 + col  (16 KB x2 buf x3 split)
// Frag reads hit 16 consecutive chunks per lane-group => 2-way bank aliasing (free).
// A ds_writes and B global_load_lds dests are linear in tid => conflict-free.
__global__ __launch_bounds__(512, 2) void fused_scorer_mfma(
    const float* __restrict__ X,           // (65536, 512)
    const __bf16* __restrict__ w1t_h,      // (256, 512)
    const __bf16* __restrict__ w1t_m,
    const __bf16* __restrict__ w1t_l,
    const float* __restrict__ b1,          // (256)
    const float* __restrict__ W2,          // (256)
    const float* __restrict__ b2p,         // scalar
    const float* __restrict__ base_logits, // (512)
    float* __restrict__ logits)            // (65536)
{
    __shared__ bf16x8 Ah[2][512], Am[2][512], Al[2][512];    // 48 KB
    __shared__ bf16x8 Bh[2][1024], Bm[2][1024], Bl[2][1024]; // 96 KB
    __shared__ float red[4][128];                            // 2 KB

    const int tid  = threadIdx.x;
    const int lane = tid & 63;
    const int wave = tid >> 6;           // 0..7
    const int wm   = (wave >> 2) << 6;   // 0 / 64
    const int wn   = (wave & 3) << 6;    // 0,64,128,192
    const int l15  = lane & 15;
    const int lg   = lane >> 4;          // 0..3
    const int row0 = blockIdx.x * 128;

    // A staging: thread t -> chunk t: row = t&127, kchunk = t>>7 (8 consecutive k)
    const float* xp = X + (size_t)(row0 + (tid & 127)) * D_DIM + (tid >> 7) * 8;
    // B staging: thread t -> chunks t and t+512 (col = t&255, kchunk = t>>8 and 2+(t>>8))
    const int bcol = tid & 255;
    const int bk1  = (tid >> 8) * 8;   // 0 or 8
    const int bk2  = bk1 + 16;         // 16 or 24

    f32x4 acc[4][4];
    #pragma unroll
    for (int mi = 0; mi < 4; ++mi)
        #pragma unroll
        for (int nj = 0; nj < 4; ++nj)
            acc[mi][nj] = (f32x4){0.f, 0.f, 0.f, 0.f};

    float b1v[4], w2v[4];
    #pragma unroll
    for (int nj = 0; nj < 4; ++nj) {
        int col = wn + nj * 16 + l15;
        b1v[nj] = b1[col];
        w2v[nj] = W2[col];
    }

    // split 8 floats -> bf16 h/m/l chunk, store at chunk index tid (ds_write_b128)
    auto split_write = [&](int buf, float4 va, float4 vb) {
        float e[8] = {va.x, va.y, va.z, va.w, vb.x, vb.y, vb.z, vb.w};
        bf16x8 hh, mm, ll;
        #pragma unroll
        for (int j = 0; j < 8; ++j) {
            float x = e[j];
            __bf16 h = (__bf16)x;
            float r1 = x - (float)h;
            __bf16 m = (__bf16)r1;
            float r2 = r1 - (float)m;
            hh[j] = h; mm[j] = m; ll[j] = (__bf16)r2;
        }
        Ah[buf][tid] = hh;
        Am[buf][tid] = mm;
        Al[buf][tid] = ll;
    };
    auto stage_b = [&](int buf, int kc) {
        size_t s1 = (size_t)bcol * D_DIM + kc + bk1;
        size_t s2 = (size_t)bcol * D_DIM + kc + bk2;
        gload_lds16(w1t_h + s1, &Bh[buf][tid]);
        gload_lds16(w1t_h + s2, &Bh[buf][tid + 512]);
        gload_lds16(w1t_m + s1, &Bm[buf][tid]);
        gload_lds16(w1t_m + s2, &Bm[buf][tid + 512]);
        gload_lds16(w1t_l + s1, &Bl[buf][tid]);
        gload_lds16(w1t_l + s2, &Bl[buf][tid + 512]);
    };

    // ---- prologue: stage k-step 0; issue xraw(1) ----
    float4 xa = *reinterpret_cast<const float4*>(xp);
    float4 xb = *reinterpret_cast<const float4*>(xp + 4);
    stage_b(0, 0);
    split_write(0, xa, xb);
    xa = *reinterpret_cast<const float4*>(xp + 32);
    xb = *reinterpret_cast<const float4*>(xp + 36);
    __syncthreads();

    for (int ks = 0; ks < 16; ++ks) {
        const int buf = ks & 1, nbuf = buf ^ 1;
        // stage B(ks+1) early (DMA lands under the MFMA block)
        stage_b(nbuf, ((ks + 1) * 32) & 511);
        // split xraw(ks+1) -> A[nbuf], then issue xraw(ks+2)
        split_write(nbuf, xa, xb);
        const int k2 = ((ks + 2) * 32) & 511;
        xa = *reinterpret_cast<const float4*>(xp + k2);
        xb = *reinterpret_cast<const float4*>(xp + k2 + 4);
        // fragments for this k-step (conflict-free chunk-major reads)
        bf16x8 fah[4], fam[4], fal[4], fbh[4], fbm[4], fbl[4];
        #pragma unroll
        for (int mi = 0; mi < 4; ++mi) {
            int ca = lg * 128 + wm + mi * 16 + l15;
            fah[mi] = Ah[buf][ca];
            fam[mi] = Am[buf][ca];
            fal[mi] = Al[buf][ca];
        }
        #pragma unroll
        for (int nj = 0; nj < 4; ++nj) {
            int cb = lg * 256 + wn + nj * 16 + l15;
            fbh[nj] = Bh[buf][cb];
            fbm[nj] = Bm[buf][cb];
            fbl[nj] = Bl[buf][cb];
        }
        // 96 MFMAs: 6 products per (mi,nj)
        #pragma unroll
        for (int mi = 0; mi < 4; ++mi)
            #pragma unroll
            for (int nj = 0; nj < 4; ++nj) {
                acc[mi][nj] = __builtin_amdgcn_mfma_f32_16x16x32_bf16(fah[mi], fbh[nj], acc[mi][nj], 0, 0, 0);
                acc[mi][nj] = __builtin_amdgcn_mfma_f32_16x16x32_bf16(fah[mi], fbm[nj], acc[mi][nj], 0, 0, 0);
                acc[mi][nj] = __builtin_amdgcn_mfma_f32_16x16x32_bf16(fam[mi], fbh[nj], acc[mi][nj], 0, 0, 0);
                acc[mi][nj] = __builtin_amdgcn_mfma_f32_16x16x32_bf16(fah[mi], fbl[nj], acc[mi][nj], 0, 0, 0);
                acc[mi][nj] = __builtin_amdgcn_mfma_f32_16x16x32_bf16(fam[mi], fbm[nj], acc[mi][nj], 0, 0, 0);
                acc[mi][nj] = __builtin_amdgcn_mfma_f32_16x16x32_bf16(fal[mi], fbh[nj], acc[mi][nj], 0, 0, 0);
            }
        __syncthreads();
    }

    // ---- epilogue: bias + exact GELU + dot W2; reduce 16 lanes then 4 waves ----
    float part[4][4];
    #pragma unroll
    for (int mi = 0; mi < 4; ++mi)
        #pragma unroll
        for (int r = 0; r < 4; ++r)
            part[mi][r] = 0.f;
    #pragma unroll
    for (int mi = 0; mi < 4; ++mi)
        #pragma unroll
        for (int nj = 0; nj < 4; ++nj)
            #pragma unroll
            for (int r = 0; r < 4; ++r) {
                float z = acc[mi][nj][r] + b1v[nj];
                float g = 0.5f * z * (1.0f + erff(z * 0.70710678118654752440f));
                part[mi][r] = fmaf(g, w2v[nj], part[mi][r]);
            }
    #pragma unroll
    for (int mi = 0; mi < 4; ++mi)
        #pragma unroll
        for (int r = 0; r < 4; ++r) {
            float v = part[mi][r];
            v += __shfl_xor(v, 1, 16);
            v += __shfl_xor(v, 2, 16);
            v += __shfl_xor(v, 4, 16);
            v += __shfl_xor(v, 8, 16);
            if (l15 == 0)
                red[wave & 3][wm + mi * 16 + lg * 4 + r] = v;
        }
    __syncthreads();
    if (tid < 128) {
        float s = red[0][tid] + red[1][tid] + red[2][tid] + red[3][tid];
        int grow = row0 + tid;
        logits[grow] = s + b2p[0] + base_logits[grow & (N_DIM - 1)];
    }
}

// ---------------- Kernel 2: softmax + top-8 + mask/importance/indices ----------------
__global__ __launch_bounds__(256) void softmax_topk_kernel(
    const float* __restrict__ logits,
    float* __restrict__ out_mask,
    float* __restrict__ out_importance,
    float* __restrict__ out_indices)
{
    const int b = blockIdx.x;
    const int tid = threadIdx.x;
    __shared__ float probs[N_DIM];
    __shared__ float redf[4];
    __shared__ int   redi[4];
    __shared__ int   sel_idx[K_SEL];

    float l0 = logits[b * N_DIM + tid];
    float l1 = logits[b * N_DIM + tid + 256];

    float m = fmaxf(l0, l1);
    #pragma unroll
    for (int s = 32; s >= 1; s >>= 1) m = fmaxf(m, __shfl_xor(m, s, 64));
    if ((tid & 63) == 0) redf[tid >> 6] = m;
    __syncthreads();
    float gm = fmaxf(fmaxf(redf[0], redf[1]), fmaxf(redf[2], redf[3]));
    __syncthreads();

    float e0 = expf(l0 - gm), e1 = expf(l1 - gm);
    float ssum = e0 + e1;
    #pragma unroll
    for (int s = 32; s >= 1; s >>= 1) ssum += __shfl_xor(ssum, s, 64);
    if ((tid & 63) == 0) redf[tid >> 6] = ssum;
    __syncthreads();
    float denom = redf[0] + redf[1] + redf[2] + redf[3];
    float p0 = e0 / denom, p1 = e1 / denom;
    probs[tid] = p0;
    probs[tid + 256] = p1;
    out_importance[b * N_DIM + tid] = p0;
    out_importance[b * N_DIM + tid + 256] = p1;
    __syncthreads();

    for (int it = 0; it < K_SEL; ++it) {
        float v0 = probs[tid]; int i0 = tid;
        float v1 = probs[tid + 256];
        if (v1 > v0) { v0 = v1; i0 = tid + 256; }
        #pragma unroll
        for (int s = 32; s >= 1; s >>= 1) {
            float ov = __shfl_xor(v0, s, 64);
            int   oi = __shfl_xor(i0, s, 64);
            if (ov > v0 || (ov == v0 && oi < i0)) { v0 = ov; i0 = oi; }
        }
        if ((tid & 63) == 0) { redf[tid >> 6] = v0; redi[tid >> 6] = i0; }
        __syncthreads();
        if (tid == 0) {
            float bv = redf[0]; int bi = redi[0];
            for (int w = 1; w < 4; ++w)
                if (redf[w] > bv || (redf[w] == bv && redi[w] < bi)) { bv = redf[w]; bi = redi[w]; }
            sel_idx[it] = bi;
            probs[bi] = -1.0f;
        }
        __syncthreads();
    }

    float mk0 = 0.f, mk1 = 0.f;
    #pragma unroll
    for (int i = 0; i < K_SEL; ++i) {
        if (sel_idx[i] == tid)       mk0 = 1.f;
        if (sel_idx[i] == tid + 256) mk1 = 1.f;
    }
    out_mask[b * N_DIM + tid] = mk0;
    out_mask[b * N_DIM + tid + 256] = mk1;

    if (tid < K_SEL) out_indices[b * K_SEL + tid] = (float)sel_idx[tid];
}

// ---------------- Kernel 3: gather selected rows (overwrites scratch last) ----------
__global__ __launch_bounds__(256) void gather_kernel(
    const float* __restrict__ X,
    const float* __restrict__ out_indices,
    float* __restrict__ out_selected)
{
    const int b = blockIdx.x;
    const int tid = threadIdx.x;
    __shared__ int sel[K_SEL];
    if (tid < K_SEL) sel[tid] = (int)out_indices[b * K_SEL + tid];
    __syncthreads();
    #pragma unroll
    for (int i = 0; i < 4; ++i) {
        int f = tid + 256 * i;
        int ki = f >> 7;
        int c4 = f & 127;
        float4 v = reinterpret_cast<const float4*>(
            X + ((size_t)b * N_DIM + sel[ki]) * D_DIM)[c4];
        reinterpret_cast<float4*>(
            out_selected + ((size_t)b * K_SEL + ki) * D_DIM)[c4] = v;
    }
}

extern "C" void kernel_launch(void* const* d_in, const int* in_sizes, int n_in,
                              void* d_out, int out_size, void* d_ws, size_t ws_size,
                              hipStream_t stream) {
    const float* X           = (const float*)d_in[0];
    const float* W1          = (const float*)d_in[1];
    const float* b1          = (const float*)d_in[2];
    const float* W2          = (const float*)d_in[3];
    const float* b2          = (const float*)d_in[4];
    const float* base_logits = (const float*)d_in[5];

    float* out            = (float*)d_out;
    float* out_selected   = out;                                  // 128*8*512 = 524288
    float* out_mask       = out_selected + B_DIM * K_SEL * D_DIM; // 128*512
    float* out_importance = out_mask + B_DIM * N_DIM;             // 128*512
    float* out_indices    = out_importance + B_DIM * N_DIM;       // 128*8

    // Scratch inside out_selected's region (gather overwrites it last):
    float*  logits = out_selected;                       // [0, 65536)
    __bf16* w1t_h  = (__bf16*)(out_selected + 65536);    // 131072 bf16
    __bf16* w1t_m  = (__bf16*)(out_selected + 131072);
    __bf16* w1t_l  = (__bf16*)(out_selected + 196608);

    hipLaunchKernelGGL(prep_w1_kernel, dim3(H_DIM), dim3(256), 0, stream,
                       W1, w1t_h, w1t_m, w1t_l);
    hipLaunchKernelGGL(fused_scorer_mfma, dim3((B_DIM * N_DIM) / 128), dim3(512), 0, stream,
                       X, w1t_h, w1t_m, w1t_l, b1, W2, b2, base_logits, logits);
    hipLaunchKernelGGL(softmax_topk_kernel, dim3(B_DIM), dim3(256), 0, stream,
                       logits, out_mask, out_importance, out_indices);
    hipLaunchKernelGGL(gather_kernel, dim3(B_DIM), dim3(256), 0, stream,
                       X, out_indices, out_selected);
}